// Round 16
// baseline (419.903 us; speedup 1.0000x reference)
//
#include <hip/hip_runtime.h>
#include <hip/hip_bf16.h>

#define HID 64

typedef float f32x4 __attribute__((ext_vector_type(4)));

// ---- bf16 helpers ----
__device__ __forceinline__ unsigned short f2bf(float f) {  // RNE f32->bf16
    unsigned u = __float_as_uint(f);
    return (unsigned short)((u + 0x7fffu + ((u >> 16) & 1u)) >> 16);
}
__device__ __forceinline__ float bfu(unsigned short u) {
    return __uint_as_float(((unsigned)u) << 16);
}

// ================= CSR build (by dst) =================

__global__ __launch_bounds__(256) void hist_part_kernel(
    const int* __restrict__ dst, int* __restrict__ cnt, int E, int psz) {
    int part = blockIdx.x & 7, chunk = blockIdx.x >> 3;
    int i = chunk * 256 + threadIdx.x;
    if (i >= E) return;
    int d = __builtin_nontemporal_load(&dst[i]);
    if (d / psz == part) atomicAdd(&cnt[d], 1);
}

__global__ __launch_bounds__(256) void bsum_kernel(const int* __restrict__ cnt,
                                                   int* __restrict__ bsums, int N) {
    __shared__ int s[256];
    int tid = threadIdx.x, i = blockIdx.x * 256 + tid;
    s[tid] = (i < N) ? cnt[i] : 0;
    __syncthreads();
    for (int o = 128; o > 0; o >>= 1) {
        if (tid < o) s[tid] += s[tid + o];
        __syncthreads();
    }
    if (tid == 0) bsums[blockIdx.x] = s[0];
}

__global__ __launch_bounds__(512) void scan_bsums_kernel(int* __restrict__ bsums, int nblk) {
    __shared__ int s[512];
    int tid = threadIdx.x;
    int orig = (tid < nblk) ? bsums[tid] : 0;
    s[tid] = orig;
    __syncthreads();
    for (int off = 1; off < 512; off <<= 1) {
        int v = (tid >= off) ? s[tid - off] : 0;
        __syncthreads();
        s[tid] += v;
        __syncthreads();
    }
    if (tid < nblk) bsums[tid] = s[tid] - orig;
}

// nodeinfo[n] = {row_ptr, deg, bits(dinv), 0}
__global__ __launch_bounds__(256) void rowptr_kernel(
    const int* __restrict__ cnt, const int* __restrict__ bsums,
    int4* __restrict__ nodeinfo, int* __restrict__ cursor, int N) {
    __shared__ int s[256];
    int tid = threadIdx.x, i = blockIdx.x * 256 + tid;
    int c = (i < N) ? cnt[i] : 0;
    s[tid] = c;
    __syncthreads();
    for (int off = 1; off < 256; off <<= 1) {
        int v = (tid >= off) ? s[tid - off] : 0;
        __syncthreads();
        s[tid] += v;
        __syncthreads();
    }
    if (i < N) {
        int excl = s[tid] - c + bsums[blockIdx.x];
        cursor[i] = excl;
        int4 ni;
        ni.x = excl;
        ni.y = c;
        ni.z = (int)__float_as_uint(rsqrtf((float)c + 1.0f));  // +1 self-loop
        ni.w = 0;
        nodeinfo[i] = ni;
    }
}

__global__ __launch_bounds__(256) void fill_part_kernel(
    const int* __restrict__ src, const int* __restrict__ dst,
    int* __restrict__ cursor, int* __restrict__ col, int E, int psz) {
    int part = blockIdx.x & 7, chunk = blockIdx.x >> 3;
    int i = chunk * 256 + threadIdx.x;
    if (i >= E) return;
    int d = __builtin_nontemporal_load(&dst[i]);
    if (d / psz == part) {
        int s = __builtin_nontemporal_load(&src[i]);
        int p = atomicAdd(&cursor[d], 1);
        col[p] = s;
    }
}

// ================= conv1 GEMM: g = bf16((X@W)*dinv) (r13, unchanged) =======

__global__ __launch_bounds__(256) void gemm_scale_kernel(
    const float* __restrict__ X, const float* __restrict__ W,
    const int4* __restrict__ nodeinfo, unsigned short* __restrict__ g, int N) {
    __shared__ float Ws[HID * HID];
    __shared__ float xs[4][HID];
    int tid = threadIdx.x;
    for (int i = tid; i < HID * HID; i += 256) Ws[i] = W[i];
    __syncthreads();
    int w = tid >> 6, c = tid & 63;
    float* xsw = xs[w];
    int ngrp = (N + 3) / 4;
    for (int grp = blockIdx.x; grp < ngrp; grp += gridDim.x) {
        int row = grp * 4 + w;
        if (row >= N) continue;
        xsw[c] = __builtin_nontemporal_load(&X[(size_t)row * HID + c]);
        float dn = __uint_as_float((unsigned)__builtin_amdgcn_readfirstlane(nodeinfo[row].z));
        float acc = 0.f;
#pragma unroll
        for (int k = 0; k < HID; ++k) acc = fmaf(xsw[k], Ws[k * HID + c], acc);
        __builtin_nontemporal_store(f2bf(acc * dn), &g[(size_t)row * HID + c]);
    }
}

// ================= lane-owns-feature gather =================
// Lane l accumulates feature l (f32). col indices are WAVE-UNIFORM (beg+j with
// uniform beg, uniform j) -> compiler emits scalar loads; per edge: one
// independent coalesced 128B row read + 2 VALU. No shfl distribution, no
// cross-lane reduce. 4 rotating accumulators + unroll -> 8+ loads in flight.
__device__ __forceinline__ float gather_lane(
    const unsigned short* __restrict__ gb, const int* __restrict__ col,
    int beg, int deg, int n, int lane) {
    float a0 = 0.f, a1 = 0.f, a2 = 0.f, a3 = 0.f;
    int j = 0;
#pragma unroll 2
    for (; j + 4 <= deg; j += 4) {
        int s0 = col[beg + j + 0];
        int s1 = col[beg + j + 1];
        int s2 = col[beg + j + 2];
        int s3 = col[beg + j + 3];
        unsigned short u0 = gb[(size_t)s0 * HID + lane];
        unsigned short u1 = gb[(size_t)s1 * HID + lane];
        unsigned short u2 = gb[(size_t)s2 * HID + lane];
        unsigned short u3 = gb[(size_t)s3 * HID + lane];
        a0 += bfu(u0); a1 += bfu(u1); a2 += bfu(u2); a3 += bfu(u3);
    }
    for (; j < deg; ++j) {
        int s0 = col[beg + j];
        a0 += bfu(gb[(size_t)s0 * HID + lane]);
    }
    a0 += bfu(gb[(size_t)n * HID + lane]);  // self-loop
    return (a0 + a1) + (a2 + a3);
}

// ---- register 8x8-block GEMM butterfly (r14-proven) ----
__device__ __forceinline__ float reggemm_butterfly(
    const unsigned* Wp, const float* o, int s) {
    float p[8] = {};
#pragma unroll
    for (int j = 0; j < 8; ++j) {
        float oj = o[j];
#pragma unroll
        for (int i2 = 0; i2 < 4; ++i2) {
            unsigned wv = Wp[j * 4 + i2];
            p[2 * i2]     = fmaf(oj, __uint_as_float(wv << 16), p[2 * i2]);
            p[2 * i2 + 1] = fmaf(oj, __uint_as_float(wv & 0xffff0000u), p[2 * i2 + 1]);
        }
    }
    bool b0 = (s & 1) != 0;
    float q1[4];
#pragma unroll
    for (int m = 0; m < 4; ++m) {
        float A = __shfl_xor(p[2 * m], 1, 64);
        float B = __shfl_xor(p[2 * m + 1], 1, 64);
        q1[m] = b0 ? (p[2 * m + 1] + B) : (p[2 * m] + A);
    }
    bool b1 = ((s >> 1) & 1) != 0;
    float q2[2];
#pragma unroll
    for (int m = 0; m < 2; ++m) {
        float A = __shfl_xor(q1[2 * m], 2, 64);
        float B = __shfl_xor(q1[2 * m + 1], 2, 64);
        q2[m] = b1 ? (q1[2 * m + 1] + B) : (q1[2 * m] + A);
    }
    bool b2 = ((s >> 2) & 1) != 0;
    float A = __shfl_xor(q2[0], 4, 64);
    float B = __shfl_xor(q2[1], 4, 64);
    return b2 ? (q2[1] + B) : (q2[0] + A);
}

// ================= fused aggregate + epilogue + next-conv GEMM =============
// gather (lane-owns-feature) -> 8-bpermute transpose into 8-feat slices ->
// register-W butterfly GEMM. (256,2) so Wp[32] stays resident (r15's VGPR=64
// showed the compiler was reloading W under the (256,4) cap).

template <bool RELU>
__global__ __launch_bounds__(256, 2) void agg_gemm_kernel(
    const unsigned short* __restrict__ g_in, const int4* __restrict__ nodeinfo,
    const int* __restrict__ col, const float* __restrict__ bias,
    const float* __restrict__ W, unsigned short* __restrict__ g_out, int N) {
    int tid = threadIdx.x, w = tid >> 6, lane = tid & 63;
    int s = lane & 7, q = lane >> 3;
    unsigned Wp[32];
#pragma unroll
    for (int j = 0; j < 8; ++j)
#pragma unroll
        for (int i2 = 0; i2 < 4; ++i2) {
            float w0 = W[(8 * s + j) * HID + 8 * q + 2 * i2];
            float w1 = W[(8 * s + j) * HID + 8 * q + 2 * i2 + 1];
            Wp[j * 4 + i2] = (unsigned)f2bf(w0) | ((unsigned)f2bf(w1) << 16);
        }
    float bb[8];
#pragma unroll
    for (int j = 0; j < 8; ++j) bb[j] = bias[8 * s + j];
    const int ngrp = (N + 3) / 4;
    for (int grp = blockIdx.x; grp < ngrp; grp += gridDim.x) {
        int n = grp * 4 + w;
        if (n >= N) continue;
        int4 ni = nodeinfo[n];
        int beg = __builtin_amdgcn_readfirstlane(ni.x);
        int deg = __builtin_amdgcn_readfirstlane(ni.y);
        float dn = __uint_as_float((unsigned)__builtin_amdgcn_readfirstlane(ni.z));
        float acc = gather_lane(g_in, col, beg, deg, n, lane);
        // transpose: lane (s,q) collects its 8-feat slice t[j] = feat 8s+j
        float t[8];
#pragma unroll
        for (int j = 0; j < 8; ++j) t[j] = __shfl(acc, 8 * s + j, 64);
        float o[8];
#pragma unroll
        for (int j = 0; j < 8; ++j) {
            o[j] = fmaf(dn, t[j], bb[j]);
            if (RELU) o[j] = fmaxf(o[j], 0.f);
        }
        float r = reggemm_butterfly(Wp, o, s);
        __builtin_nontemporal_store(f2bf(r * dn), &g_out[(size_t)n * HID + lane]);
    }
}

// ================= final aggregate + bias + log_softmax ====================
// lane-owns-feature: no transpose needed; 6-round wave reduce for max/sum.

__global__ __launch_bounds__(256) void agg_lsm_kernel(
    const unsigned short* __restrict__ g_in, const int4* __restrict__ nodeinfo,
    const int* __restrict__ col, const float* __restrict__ bias,
    float* __restrict__ out, int N) {
    int tid = threadIdx.x, w = tid >> 6, lane = tid & 63;
    float bl = bias[lane];
    const int ngrp = (N + 3) / 4;
    for (int grp = blockIdx.x; grp < ngrp; grp += gridDim.x) {
        int n = grp * 4 + w;
        if (n >= N) continue;
        int4 ni = nodeinfo[n];
        int beg = __builtin_amdgcn_readfirstlane(ni.x);
        int deg = __builtin_amdgcn_readfirstlane(ni.y);
        float dn = __uint_as_float((unsigned)__builtin_amdgcn_readfirstlane(ni.z));
        float t = gather_lane(g_in, col, beg, deg, n, lane);
        float v = fmaf(dn, t, bl);
        float mx = v;
#pragma unroll
        for (int o = 1; o < 64; o <<= 1) mx = fmaxf(mx, __shfl_xor(mx, o, 64));
        float sum = expf(v - mx);
#pragma unroll
        for (int o = 1; o < 64; o <<= 1) sum += __shfl_xor(sum, o, 64);
        __builtin_nontemporal_store(v - mx - logf(sum), &out[(size_t)n * HID + lane]);
    }
}

// ================= launcher =================

static inline size_t alignup(size_t x) { return (x + 255) & ~(size_t)255; }

extern "C" void kernel_launch(void* const* d_in, const int* in_sizes, int n_in,
                              void* d_out, int out_size, void* d_ws, size_t ws_size,
                              hipStream_t stream) {
    const float* x  = (const float*)d_in[0];
    const int*   ei = (const int*)d_in[1];
    const float* W1 = (const float*)d_in[2];
    const float* b1 = (const float*)d_in[3];
    const float* W2 = (const float*)d_in[4];
    const float* b2 = (const float*)d_in[5];

    const int N = in_sizes[0] / HID;  // 100000
    const int E = in_sizes[1] / 2;    // 1600000
    const int* src = ei;
    const int* dst = ei + E;

    const int nblk = (N + 255) / 256;  // 391 (<=512 required by scan)
    const int psz  = (N + 7) / 8;      // dst-range partition size

    char* w = (char*)d_ws;
    unsigned short* gA       = (unsigned short*)w; w += alignup((size_t)(N + 1) * HID * 2);
    unsigned short* gB       = (unsigned short*)w; w += alignup((size_t)(N + 1) * HID * 2);
    int4*           nodeinfo = (int4*)w;           w += alignup((size_t)N * 16);
    int*            cnt      = (int*)w;            w += alignup((size_t)N * 4);
    int*            cursor   = (int*)w;            w += alignup((size_t)N * 4);
    int*            col      = (int*)w;            w += alignup((size_t)E * 4);
    int*            bsums    = (int*)w;            w += alignup((size_t)nblk * 4);

    const int egrid  = (E + 255) / 256;
    const int gsgrid = 2048;  // grid-stride kernels

    // ---- CSR build (once; reused by all 3 convs) ----
    (void)hipMemsetAsync(cnt, 0, (size_t)N * sizeof(int), stream);
    hist_part_kernel<<<egrid * 8, 256, 0, stream>>>(dst, cnt, E, psz);
    bsum_kernel<<<nblk, 256, 0, stream>>>(cnt, bsums, N);
    scan_bsums_kernel<<<1, 512, 0, stream>>>(bsums, nblk);
    rowptr_kernel<<<nblk, 256, 0, stream>>>(cnt, bsums, nodeinfo, cursor, N);
    fill_part_kernel<<<egrid * 8, 256, 0, stream>>>(src, dst, cursor, col, E, psz);

    // ---- conv1 GEMM: gA = (x@W1)*dinv ----
    gemm_scale_kernel<<<gsgrid, 256, 0, stream>>>(x, W1, nodeinfo, gA, N);
    // ---- conv1 agg + b1 | conv2 GEMM: gB = ((agg(gA)+b1)@W1)*dinv ----
    agg_gemm_kernel<false><<<gsgrid, 256, 0, stream>>>(gA, nodeinfo, col, b1, W1, gB, N);
    // ---- conv2 agg + b1 + relu | conv3 GEMM: gA = (relu(agg(gB)+b1)@W2)*dinv ----
    agg_gemm_kernel<true><<<gsgrid, 256, 0, stream>>>(gB, nodeinfo, col, b1, W2, gA, N);
    // ---- conv3 agg + b2 + log_softmax -> d_out ----
    agg_lsm_kernel<<<gsgrid, 256, 0, stream>>>(gA, nodeinfo, col, b2, (float*)d_out, N);
}